// Round 6
// baseline (1949.610 us; speedup 1.0000x reference)
//
#include <hip/hip_runtime.h>

typedef _Float16 v8h __attribute__((ext_vector_type(8)));
typedef _Float16 v4h __attribute__((ext_vector_type(4)));
typedef float    v4f __attribute__((ext_vector_type(4)));

#define GK 6432      // true K / N of the big GEMM
#define GN 6432
#define GM 2048
#define KP 6528      // K padded to 102*64 for BK=64 pipeline

// ---------------------------------------------------------------------------
// Weight conversion: wl fp32 [6432,6432] -> fp16 [6432, KP], K-pad cols zeroed
// ---------------------------------------------------------------------------
__global__ void convert_w(const float* __restrict__ wl, _Float16* __restrict__ Wh)
{
    const int row = blockIdx.y;                       // 0..6431
    const int col = (blockIdx.x * 256 + threadIdx.x) * 4;
    if (col >= KP) return;
    v4h h;
    if (col < GK) {
        const float4 f = *(const float4*)(wl + (long)row * GK + col);
        h[0] = (_Float16)f.x; h[1] = (_Float16)f.y;
        h[2] = (_Float16)f.z; h[3] = (_Float16)f.w;
    } else {
        h[0] = (_Float16)0.f; h[1] = (_Float16)0.f;
        h[2] = (_Float16)0.f; h[3] = (_Float16)0.f;
    }
    *(v4h*)(Wh + (long)row * KP + col) = h;
}

// ---------------------------------------------------------------------------
// Multi-scale conv feature extractor (unchanged). F0 [2048, KP] fp16.
// ---------------------------------------------------------------------------
#define SX   0
#define SX2  2048
#define SX4  3136
#define SW1  3712
#define SB1  4032
#define SW2  4048
#define SB2  6608
#define SP1  6640
#define LDSZ 13808

__global__ __launch_bounds__(256) void conv_feat(
    const float* __restrict__ x,
    const float* __restrict__ w1, const float* __restrict__ b1,
    const float* __restrict__ w2, const float* __restrict__ b2,
    _Float16* __restrict__ F0)
{
    __shared__ float lds[LDSZ];
    const int tid = threadIdx.x;
    const long b  = blockIdx.x;

    for (int i = tid; i < 1920; i += 256) {
        int c = i / 480, t = i % 480;
        lds[SX + c * 512 + t] = x[(b * 4 + c) * 480 + t];
    }
    for (int i = tid; i < 320;  i += 256) lds[SW1 + i] = w1[i];
    for (int i = tid; i < 16;   i += 256) lds[SB1 + i] = b1[i];
    for (int i = tid; i < 2560; i += 256) lds[SW2 + i] = w2[i];
    for (int i = tid; i < 32;   i += 256) lds[SB2 + i] = b2[i];
    for (int i = tid; i < KP - GK; i += 256) F0[b * KP + GK + i] = (_Float16)0.f;
    __syncthreads();

    for (int i = tid; i < 960; i += 256) {
        int c = i / 240, t = i % 240;
        lds[SX2 + c * 272 + t] = 0.5f * (lds[SX + c * 512 + 2 * t] + lds[SX + c * 512 + 2 * t + 1]);
    }
    for (int i = tid; i < 480; i += 256) {
        int c = i / 120, t = i % 120;
        float s = lds[SX + c * 512 + 4 * t]     + lds[SX + c * 512 + 4 * t + 1]
                + lds[SX + c * 512 + 4 * t + 2] + lds[SX + c * 512 + 4 * t + 3];
        lds[SX4 + c * 144 + t] = 0.25f * s;
    }
    __syncthreads();

    for (int jid = tid; jid < 16 * 34; jid += 256) {
        const int c1 = jid / 34, rid = jid % 34;
        const int sidx = (rid < 19) ? 0 : (rid < 29 ? 1 : 2);
        const int r0   = (sidx == 0) ? rid : (sidx == 1 ? rid - 19 : rid - 29);
        const int u0   = r0 * 13;
        const int xbase  = (sidx == 0) ? SX  : (sidx == 1 ? SX2 : SX4);
        const int xpitch = (sidx == 0) ? 512 : (sidx == 1 ? 272 : 144);
        const int P      = (sidx == 0) ? 238 : (sidx == 1 ? 118 : 58);
        const int pofs   = (sidx == 0) ? 0   : (sidx == 1 ? 238 : 356);

        float acc[26];
        const float bias = lds[SB1 + c1];
        #pragma unroll
        for (int i = 0; i < 26; ++i) acc[i] = bias;

        #pragma unroll
        for (int ci = 0; ci < 4; ++ci) {
            float w[30];
            const float* xr = &lds[xbase + ci * xpitch + 2 * u0];
            #pragma unroll
            for (int q = 0; q < 15; ++q) {
                float2 t2 = *(const float2*)(xr + 2 * q);
                w[2 * q] = t2.x; w[2 * q + 1] = t2.y;
            }
            float wt[5];
            #pragma unroll
            for (int k = 0; k < 5; ++k) wt[k] = lds[SW1 + (c1 * 4 + ci) * 5 + k];
            #pragma unroll
            for (int i = 0; i < 26; ++i) {
                #pragma unroll
                for (int k = 0; k < 5; ++k) acc[i] += w[i + k] * wt[k];
            }
        }
        #pragma unroll
        for (int i = 0; i < 13; ++i) {
            int u = u0 + i;
            if (u < P)
                lds[SP1 + c1 * 448 + pofs + u] = fmaxf(fmaxf(acc[2 * i], acc[2 * i + 1]), 0.f);
        }
    }
    __syncthreads();

    for (int jid = tid; jid < 32 * 17; jid += 256) {
        const int c2 = jid / 17, rid = jid % 17;
        const int sidx = (rid < 9) ? 0 : (rid < 14 ? 1 : 2);
        const int r0   = (sidx == 0) ? rid : (sidx == 1 ? rid - 9 : rid - 14);
        const int v0   = r0 * 13;
        const int pbase = (sidx == 0) ? 0   : (sidx == 1 ? 238 : 356);
        const int Pv    = (sidx == 0) ? 117 : (sidx == 1 ? 57  : 27);
        const int vout  = (sidx == 0) ? 0   : (sidx == 1 ? 117 : 174);

        float acc[26];
        const float bias = lds[SB2 + c2];
        #pragma unroll
        for (int i = 0; i < 26; ++i) acc[i] = bias;

        for (int c1 = 0; c1 < 16; ++c1) {
            float w[30];
            const float* pr = &lds[SP1 + c1 * 448 + pbase + 2 * v0];
            #pragma unroll
            for (int q = 0; q < 15; ++q) {
                float2 t2 = *(const float2*)(pr + 2 * q);
                w[2 * q] = t2.x; w[2 * q + 1] = t2.y;
            }
            float wt[5];
            #pragma unroll
            for (int k = 0; k < 5; ++k) wt[k] = lds[SW2 + (c2 * 16 + c1) * 5 + k];
            #pragma unroll
            for (int i = 0; i < 26; ++i) {
                #pragma unroll
                for (int k = 0; k < 5; ++k) acc[i] += w[i + k] * wt[k];
            }
        }
        #pragma unroll
        for (int i = 0; i < 13; ++i) {
            int v = v0 + i;
            if (v < Pv) {
                float f = fmaxf(fmaxf(acc[2 * i], acc[2 * i + 1]), 0.f);
                F0[b * KP + c2 * 201 + vout + v] = (_Float16)f;
            }
        }
    }
}

// ---------------------------------------------------------------------------
// out init: out[b][o] = bo[o]  (gemm<FUSED=1> atomically accumulates on top)
// ---------------------------------------------------------------------------
__global__ __launch_bounds__(512) void out_init(const float* __restrict__ bo,
                                                float* __restrict__ out)
{
    const int i = blockIdx.x * 512 + threadIdx.x;
    if (i < GM * 5) out[i] = bo[i % 5];
}

// ---------------------------------------------------------------------------
// 256x256x(BK=64) NT GEMM, 16 waves, register-pipelined bf (counted lgkm).
// Change vs R5: each bf fragment is issued ONE FULL PHASE+BARRIER before its
// consuming MFMA cluster, into a statically-rotated register pair (bA/bB):
//   P1 issues af + bf(k0)->bA + bf(k1)->bB; MFMA(k0) waits lgkmcnt(2)
//   P2 issues bf(k2)->bA;  MFMA(k1,bB) waits lgkmcnt(2)
//   P3 issues bf(k3)->bB;  MFMA(k2,bA) waits lgkmcnt(2)
//   P4 (no reads, open barrier merged away): lgkm(0); MFMA(k3,bB)
// -> only P1's af burst keeps exposed LDS latency; 7 barriers/round (was 8).
// Staging (unchanged from R5, region-safety re-proven):
//   P1: B23(kt+1)->buf^1 (1 GLD)  [B23 of buf^1 last read at prev round
//       P1 (bf k2,k3 issued P2/P3 read stripes 2,3? no: stripes 2,3 = phases
//       2,3 fragments, issued at P2/P3 of prev round from buf^1... all buf^1
//       reads complete before prev round-final barrier -> free]
//   P2: A(kt+2)->buf (2 GLD)      [af read issued P1, freed by B1]
//   P3: B01(kt+2)->buf (1 GLD)    [bf k0,k1 issued P1, freed by B1]
// vmcnt(3) at round end: drains prev round's P2/P3 (tile kt+1's A,B01) and
// this round's P1 (tile kt+1's B23); keeps this round's P2/P3 (kt+2) in
// flight. In-order completion => tile kt+1 fully in LDS at final barrier.
// FUSED=1: skip C-write; instead out[row,:5] += relu(acc+bias) . wo^T
// (wo/bias block-slice staged to LDS, fr-lane shfl reduce, atomicAdd).
// ---------------------------------------------------------------------------
template<int FUSED>
__global__ __launch_bounds__(1024, 4) void gemm16(
    const _Float16* __restrict__ A, const _Float16* __restrict__ Bw,
    const float* __restrict__ bias, _Float16* __restrict__ C,
    const float* __restrict__ wo, float* __restrict__ outp)
{
    __shared__ _Float16 sA[2][256 * 64];   // 64 KB
    __shared__ _Float16 sB[2][256 * 64];   // total 128 KB

    const int tid  = threadIdx.x;
    const int lane = tid & 63;
    const int wave = tid >> 6;           // 0..15
    const int wm   = wave >> 2;          // m quarter (0..3)
    const int wn   = wave & 3;           // n quarter (0..3)

    const int id = blockIdx.x;           // 208 = 8 m-tiles x 26 n-tiles
    const long tile_m = (long)(id & 7) << 8;   // m-tile = XCD id: A strip L2-resident
    const long tile_n = (long)(id >> 3) << 8;

    // ---- staging geometry (linear LDS dst; pre-XOR-swizzled source) ----
    const int lrow = lane >> 3;                  // 0..7
    const int lcol = ((lane & 7) ^ lrow) << 3;   // fp16 elems

    // A: wave stages rows [wave*16, +16) (2 GLD)
    const _Float16* pAst = A + (tile_m + wave * 16 + lrow) * (long)KP + lcol;
    const int dA0 = wave * 16 * 64, dA1 = dA0 + 512;

    // B: stripes01 rows [(w>>2)*64 + (w&3)*8, +8); stripes23 = +32 (1 GLD each)
    const int bRow01 = (wave >> 2) * 64 + (wave & 3) * 8;
    long rb01 = tile_n + bRow01;
    long rb23 = rb01 + 32;
    long r01l = rb01 + lrow; if (r01l > 6431) r01l = 6431;  // last-n-tile clamp:
    long r23l = rb23 + lrow; if (r23l > 6431) r23l = 6431;  // garbage cols discarded
    const _Float16* pB01 = Bw + r01l * (long)KP + lcol;
    const _Float16* pB23 = Bw + r23l * (long)KP + lcol;
    const int dB01 = bRow01 * 64;
    const int dB23 = dB01 + 32 * 64;

#define GLD(p, d) __builtin_amdgcn_global_load_lds(                          \
        (const __attribute__((address_space(1))) void*)(p),                  \
        (__attribute__((address_space(3))) void*)(d), 16, 0, 0)

#define STAGE_A(CUR, q)   { GLD(q, &sA[CUR][dA0]); GLD((q) + 8L * KP, &sA[CUR][dA1]); }
#define STAGE_B01(CUR, q) { GLD(q, &sB[CUR][dB01]); }
#define STAGE_B23(CUR, q) { GLD(q, &sB[CUR][dB23]); }

    // ---- fragment read geometry (R2-verified conflict-free swizzle) ----
    const int fr = lane & 15;
    const int fp = lane >> 4;                    // k-phase 0..3
    const int sw = fr & 7;
    const int slot0 = ((fp)     ^ sw) << 3;
    const int slot1 = ((fp + 4) ^ sw) << 3;
    const int arow0 = wm * 64 + fr;              // af row for mi=0
    const int brow0 = wn * 64 + fr;              // bf row for p=0

    v8h af[4][2], bA0, bA1, bB0, bB1;
    v4f acc[4][4];
    #pragma unroll
    for (int mi = 0; mi < 4; ++mi) {
        #pragma unroll
        for (int nf = 0; nf < 4; ++nf) { v4f z = {0.f, 0.f, 0.f, 0.f}; acc[mi][nf] = z; }
    }

#define LDAALL(CUR) { _Pragma("unroll")                                      \
    for (int mi = 0; mi < 4; ++mi) {                                         \
        af[mi][0] = *(const v8h*)&sA[CUR][(arow0 + mi * 16) * 64 + slot0];   \
        af[mi][1] = *(const v8h*)&sA[CUR][(arow0 + mi * 16) * 64 + slot1];   \
    } }

#define LDB(CUR, P, D0, D1) {                                                \
    D0 = *(const v8h*)&sB[CUR][(brow0 + (P) * 16) * 64 + slot0];             \
    D1 = *(const v8h*)&sB[CUR][(brow0 + (P) * 16) * 64 + slot1]; }

#define MMAP(P, B0, B1) { _Pragma("unroll")                                  \
    for (int mi = 0; mi < 4; ++mi) {                                         \
        acc[mi][P] = __builtin_amdgcn_mfma_f32_16x16x32_f16(af[mi][0], B0,   \
                                                            acc[mi][P], 0, 0, 0); \
        acc[mi][P] = __builtin_amdgcn_mfma_f32_16x16x32_f16(af[mi][1], B1,   \
                                                            acc[mi][P], 0, 0, 0); \
    } }

#define ROUND(CUR, S1, S2, VN) {                                             \
    /* P1: af(8) + bf(k0)->bA + bf(k1)->bB; stage B23(kt+1)->buf^1 */        \
    LDAALL(CUR); LDB(CUR, 0, bA0, bA1); LDB(CUR, 1, bB0, bB1);               \
    if (S1) STAGE_B23((CUR) ^ 1, qB23);                                      \
    __builtin_amdgcn_s_barrier();                                            \
    asm volatile("s_waitcnt lgkmcnt(2)" ::: "memory");                       \
    __builtin_amdgcn_s_setprio(1);                                           \
    MMAP(0, bA0, bA1);                                                       \
    __builtin_amdgcn_s_setprio(0);                                           \
    __builtin_amdgcn_s_barrier();                                            \
    /* P2: bf(k2)->bA; stage A(kt+2)->buf; MFMA(k1) from bB */               \
    LDB(CUR, 2, bA0, bA1);                                                   \
    if (S2) STAGE_A(CUR, qA);                                                \
    __builtin_amdgcn_s_barrier();                                            \
    asm volatile("s_waitcnt lgkmcnt(2)" ::: "memory");                       \
    __builtin_amdgcn_s_setprio(1);                                           \
    MMAP(1, bB0, bB1);                                                       \
    __builtin_amdgcn_s_setprio(0);                                           \
    __builtin_amdgcn_s_barrier();                                            \
    /* P3: bf(k3)->bB; stage B01(kt+2)->buf; MFMA(k2) from bA */             \
    LDB(CUR, 3, bB0, bB1);                                                   \
    if (S2) STAGE_B01(CUR, qB01);                                            \
    __builtin_amdgcn_s_barrier();                                            \
    asm volatile("s_waitcnt lgkmcnt(2)" ::: "memory");                       \
    __builtin_amdgcn_s_setprio(1);                                           \
    MMAP(2, bA0, bA1);                                                       \
    __builtin_amdgcn_s_setprio(0);                                           \
    __builtin_amdgcn_s_barrier();                                            \
    /* P4: MFMA(k3) from bB; counted vmcnt; round-final barrier */           \
    asm volatile("s_waitcnt lgkmcnt(0)" ::: "memory");                       \
    __builtin_amdgcn_s_setprio(1);                                           \
    MMAP(3, bB0, bB1);                                                       \
    __builtin_amdgcn_s_setprio(0);                                           \
    asm volatile("s_waitcnt vmcnt(" #VN ")" ::: "memory");                   \
    __builtin_amdgcn_s_barrier();                                            \
    qA += 64; qB01 += 64; qB23 += 64; }

    // ---- prologue: tile0 full -> buf0; tile1 {A, Bs01} -> buf1 ----
    STAGE_A(0, pAst); STAGE_B01(0, pB01); STAGE_B23(0, pB23);
    STAGE_A(1, pAst + 64); STAGE_B01(1, pB01 + 64);
    asm volatile("s_waitcnt vmcnt(3)" ::: "memory");   // tile0's 4 landed
    __builtin_amdgcn_s_barrier();

    const _Float16* qA   = pAst + 128;   // A(kt+2) source
    const _Float16* qB01 = pB01 + 128;   // B(kt+2) s01
    const _Float16* qB23 = pB23 + 64;    // B(kt+1) s23

    for (int kt = 0; kt < 100; kt += 2) {
        ROUND(0, 1, 1, 3);
        ROUND(1, 1, 1, 3);
    }
    ROUND(0, 1, 0, 0);   // kt=100: stage B(101)s23 only; drain all
    ROUND(1, 0, 0, 0);   // kt=101: compute only

    if constexpr (FUSED == 0) {
        // ---- epilogue: C/D layout col=lane&15, row=(lane>>4)*4+reg ----
        #pragma unroll
        for (int nf = 0; nf < 4; ++nf) {
            const long col = tile_n + wn * 64 + nf * 16 + fr;
            if (col < KP) {
                const bool val = col < GN;
                const float bv = val ? bias[col] : 0.f;
                #pragma unroll
                for (int mi = 0; mi < 4; ++mi) {
                    const long row = tile_m + wm * 64 + mi * 16 + fp * 4;
                    #pragma unroll
                    for (int r = 0; r < 4; ++r) {
                        float v = acc[mi][nf][r] + bv;
                        v = v > 0.f ? v : 0.f;
                        // pad cols [6432,6528) get 0 (K-pad of next GEMM's A)
                        C[(row + r) * (long)KP + col] = val ? (_Float16)v : (_Float16)0.f;
                    }
                }
            }
        }
    } else {
        // ---- fused final projection: out[row,:] += relu(acc+bias).wo^T ----
        float* fl = (float*)&sA[0][0];       // bias [256] + wo [5][256]
        __syncthreads();                      // all LDS compute reads done
        for (int i = tid; i < 256 * 6; i += 1024) {
            const int c = i & 255, j = i >> 8;     // j=0: bias; 1..5: wo rows
            const long gcol = tile_n + c;
            float v = 0.f;
            if (gcol < GN) v = (j == 0) ? bias[gcol] : wo[(long)(j - 1) * GK + gcol];
            fl[j * 256 + c] = v;
        }
        __syncthreads();
        const float* biasL = fl;
        const float* woL   = fl + 256;
        #pragma unroll
        for (int mi = 0; mi < 4; ++mi) {
            #pragma unroll
            for (int r = 0; r < 4; ++r) {
                float s0 = 0.f, s1 = 0.f, s2 = 0.f, s3 = 0.f, s4 = 0.f;
                #pragma unroll
                for (int nf = 0; nf < 4; ++nf) {
                    const int cl = wn * 64 + nf * 16 + fr;
                    float v = acc[mi][nf][r] + biasL[cl];
                    v = v > 0.f ? v : 0.f;
                    s0 += v * woL[cl];
                    s1 += v * woL[256 + cl];
                    s2 += v * woL[512 + cl];
                    s3 += v * woL[768 + cl];
                    s4 += v * woL[1024 + cl];
                }
                #pragma unroll
                for (int m = 1; m < 16; m <<= 1) {
                    s0 += __shfl_xor(s0, m, 64);
                    s1 += __shfl_xor(s1, m, 64);
                    s2 += __shfl_xor(s2, m, 64);
                    s3 += __shfl_xor(s3, m, 64);
                    s4 += __shfl_xor(s4, m, 64);
                }
                if (fr == 0) {
                    const long row = tile_m + wm * 64 + mi * 16 + fp * 4 + r;
                    atomicAdd(&outp[row * 5 + 0], s0);
                    atomicAdd(&outp[row * 5 + 1], s1);
                    atomicAdd(&outp[row * 5 + 2], s2);
                    atomicAdd(&outp[row * 5 + 3], s3);
                    atomicAdd(&outp[row * 5 + 4], s4);
                }
            }
        }
    }

#undef GLD
#undef STAGE_A
#undef STAGE_B01
#undef STAGE_B23
#undef LDAALL
#undef LDB
#undef MMAP
#undef ROUND
}

// ---------------------------------------------------------------------------
extern "C" void kernel_launch(void* const* d_in, const int* in_sizes, int n_in,
                              void* d_out, int out_size, void* d_ws, size_t ws_size,
                              hipStream_t stream)
{
    const float* x  = (const float*)d_in[0];
    const float* w1 = (const float*)d_in[1];
    const float* b1 = (const float*)d_in[2];
    const float* w2 = (const float*)d_in[3];
    const float* b2 = (const float*)d_in[4];
    const float* wl = (const float*)d_in[5];
    const float* bl = (const float*)d_in[6];
    const float* wo = (const float*)d_in[7];
    const float* bo = (const float*)d_in[8];
    float* out = (float*)d_out;

    char* ws = (char*)d_ws;
    _Float16* Wh = (_Float16*)ws;                                   // 6432*6528*2 = 83,976,192 B
    _Float16* F0 = (_Float16*)(ws + 83976192);                      // 2048*6528*2 = 26,738,688 B
    _Float16* F1 = (_Float16*)(ws + 83976192 + 26738688);

    convert_w<<<dim3(7, GN), 256, 0, stream>>>(wl, Wh);
    conv_feat<<<GM, 256, 0, stream>>>(x, w1, b1, w2, b2, F0);
    gemm16<0><<<208, 1024, 0, stream>>>(F0, Wh, bl, F1, nullptr, nullptr);
    gemm16<0><<<208, 1024, 0, stream>>>(F1, Wh, bl, F0, nullptr, nullptr);
    gemm16<0><<<208, 1024, 0, stream>>>(F0, Wh, bl, F1, nullptr, nullptr);
    out_init<<<20, 512, 0, stream>>>(bo, out);
    gemm16<1><<<208, 1024, 0, stream>>>(F1, Wh, bl, nullptr, wo, out);
}

// Round 8
// 1317.408 us; speedup vs baseline: 1.4799x; 1.4799x over previous
//
#include <hip/hip_runtime.h>

typedef _Float16 v8h __attribute__((ext_vector_type(8)));
typedef _Float16 v4h __attribute__((ext_vector_type(4)));
typedef float    v4f __attribute__((ext_vector_type(4)));

#define GK 6432      // true K / N of the big GEMM
#define GN 6432
#define GM 2048
#define KP 6528      // K padded to 102*64 for BK=64 pipeline

// ---------------------------------------------------------------------------
// Weight conversion: wl fp32 [6432,6432] -> fp16 [6432, KP], K-pad cols zeroed
// ---------------------------------------------------------------------------
__global__ void convert_w(const float* __restrict__ wl, _Float16* __restrict__ Wh)
{
    const int row = blockIdx.y;                       // 0..6431
    const int col = (blockIdx.x * 256 + threadIdx.x) * 4;
    if (col >= KP) return;
    v4h h;
    if (col < GK) {
        const float4 f = *(const float4*)(wl + (long)row * GK + col);
        h[0] = (_Float16)f.x; h[1] = (_Float16)f.y;
        h[2] = (_Float16)f.z; h[3] = (_Float16)f.w;
    } else {
        h[0] = (_Float16)0.f; h[1] = (_Float16)0.f;
        h[2] = (_Float16)0.f; h[3] = (_Float16)0.f;
    }
    *(v4h*)(Wh + (long)row * KP + col) = h;
}

// ---------------------------------------------------------------------------
// Multi-scale conv feature extractor (unchanged). F0 [2048, KP] fp16.
// ---------------------------------------------------------------------------
#define SX   0
#define SX2  2048
#define SX4  3136
#define SW1  3712
#define SB1  4032
#define SW2  4048
#define SB2  6608
#define SP1  6640
#define LDSZ 13808

__global__ __launch_bounds__(256) void conv_feat(
    const float* __restrict__ x,
    const float* __restrict__ w1, const float* __restrict__ b1,
    const float* __restrict__ w2, const float* __restrict__ b2,
    _Float16* __restrict__ F0)
{
    __shared__ float lds[LDSZ];
    const int tid = threadIdx.x;
    const long b  = blockIdx.x;

    for (int i = tid; i < 1920; i += 256) {
        int c = i / 480, t = i % 480;
        lds[SX + c * 512 + t] = x[(b * 4 + c) * 480 + t];
    }
    for (int i = tid; i < 320;  i += 256) lds[SW1 + i] = w1[i];
    for (int i = tid; i < 16;   i += 256) lds[SB1 + i] = b1[i];
    for (int i = tid; i < 2560; i += 256) lds[SW2 + i] = w2[i];
    for (int i = tid; i < 32;   i += 256) lds[SB2 + i] = b2[i];
    for (int i = tid; i < KP - GK; i += 256) F0[b * KP + GK + i] = (_Float16)0.f;
    __syncthreads();

    for (int i = tid; i < 960; i += 256) {
        int c = i / 240, t = i % 240;
        lds[SX2 + c * 272 + t] = 0.5f * (lds[SX + c * 512 + 2 * t] + lds[SX + c * 512 + 2 * t + 1]);
    }
    for (int i = tid; i < 480; i += 256) {
        int c = i / 120, t = i % 120;
        float s = lds[SX + c * 512 + 4 * t]     + lds[SX + c * 512 + 4 * t + 1]
                + lds[SX + c * 512 + 4 * t + 2] + lds[SX + c * 512 + 4 * t + 3];
        lds[SX4 + c * 144 + t] = 0.25f * s;
    }
    __syncthreads();

    for (int jid = tid; jid < 16 * 34; jid += 256) {
        const int c1 = jid / 34, rid = jid % 34;
        const int sidx = (rid < 19) ? 0 : (rid < 29 ? 1 : 2);
        const int r0   = (sidx == 0) ? rid : (sidx == 1 ? rid - 19 : rid - 29);
        const int u0   = r0 * 13;
        const int xbase  = (sidx == 0) ? SX  : (sidx == 1 ? SX2 : SX4);
        const int xpitch = (sidx == 0) ? 512 : (sidx == 1 ? 272 : 144);
        const int P      = (sidx == 0) ? 238 : (sidx == 1 ? 118 : 58);
        const int pofs   = (sidx == 0) ? 0   : (sidx == 1 ? 238 : 356);

        float acc[26];
        const float bias = lds[SB1 + c1];
        #pragma unroll
        for (int i = 0; i < 26; ++i) acc[i] = bias;

        #pragma unroll
        for (int ci = 0; ci < 4; ++ci) {
            float w[30];
            const float* xr = &lds[xbase + ci * xpitch + 2 * u0];
            #pragma unroll
            for (int q = 0; q < 15; ++q) {
                float2 t2 = *(const float2*)(xr + 2 * q);
                w[2 * q] = t2.x; w[2 * q + 1] = t2.y;
            }
            float wt[5];
            #pragma unroll
            for (int k = 0; k < 5; ++k) wt[k] = lds[SW1 + (c1 * 4 + ci) * 5 + k];
            #pragma unroll
            for (int i = 0; i < 26; ++i) {
                #pragma unroll
                for (int k = 0; k < 5; ++k) acc[i] += w[i + k] * wt[k];
            }
        }
        #pragma unroll
        for (int i = 0; i < 13; ++i) {
            int u = u0 + i;
            if (u < P)
                lds[SP1 + c1 * 448 + pofs + u] = fmaxf(fmaxf(acc[2 * i], acc[2 * i + 1]), 0.f);
        }
    }
    __syncthreads();

    for (int jid = tid; jid < 32 * 17; jid += 256) {
        const int c2 = jid / 17, rid = jid % 17;
        const int sidx = (rid < 9) ? 0 : (rid < 14 ? 1 : 2);
        const int r0   = (sidx == 0) ? rid : (sidx == 1 ? rid - 9 : rid - 14);
        const int v0   = r0 * 13;
        const int pbase = (sidx == 0) ? 0   : (sidx == 1 ? 238 : 356);
        const int Pv    = (sidx == 0) ? 117 : (sidx == 1 ? 57  : 27);
        const int vout  = (sidx == 0) ? 0   : (sidx == 1 ? 117 : 174);

        float acc[26];
        const float bias = lds[SB2 + c2];
        #pragma unroll
        for (int i = 0; i < 26; ++i) acc[i] = bias;

        for (int c1 = 0; c1 < 16; ++c1) {
            float w[30];
            const float* pr = &lds[SP1 + c1 * 448 + pbase + 2 * v0];
            #pragma unroll
            for (int q = 0; q < 15; ++q) {
                float2 t2 = *(const float2*)(pr + 2 * q);
                w[2 * q] = t2.x; w[2 * q + 1] = t2.y;
            }
            float wt[5];
            #pragma unroll
            for (int k = 0; k < 5; ++k) wt[k] = lds[SW2 + (c2 * 16 + c1) * 5 + k];
            #pragma unroll
            for (int i = 0; i < 26; ++i) {
                #pragma unroll
                for (int k = 0; k < 5; ++k) acc[i] += w[i + k] * wt[k];
            }
        }
        #pragma unroll
        for (int i = 0; i < 13; ++i) {
            int v = v0 + i;
            if (v < Pv) {
                float f = fmaxf(fmaxf(acc[2 * i], acc[2 * i + 1]), 0.f);
                F0[b * KP + c2 * 201 + vout + v] = (_Float16)f;
            }
        }
    }
}

// ---------------------------------------------------------------------------
// 256x256x(BK=64) 8-phase NT GEMM -- EXACT R1 structure (best measured),
// with ONE change vs R1: chunked-XCD block mapping for B L2-reuse.
// (R7 had this but with a STAGE_A address bug -- row0*KP added twice.)
//
// OLD mapping: XCD (id&7) = m-tile -> 26 blocks/XCD share A only; each XCD
// streams the full 84MB B panel (~832KB L2-fill/XCD/round ~= 392 GB/s, the
// suspected round limiter). NEW: each XCD owns a 2m x 13n chunk: 26 blocks
// share 2 A-strips AND 13 B-strips; per-round per-XCD L2 fill =
// 13*256*64*2 (B) + 2*256*64*2 (A) = 480KB (1.87x cut), and 12/13 B reads
// hit L2 (blocks march K in loose lockstep; 4MB L2 holds ~9 rounds of B).
// ---------------------------------------------------------------------------
__global__ __launch_bounds__(512, 2) void gemm8(
    const _Float16* __restrict__ A, const _Float16* __restrict__ Bw,
    const float* __restrict__ bias, _Float16* __restrict__ C)
{
    __shared__ _Float16 sA[2][256 * 64];   // 32 KB per buf
    __shared__ _Float16 sB[2][256 * 64];   // total LDS = 128 KB

    const int tid  = threadIdx.x;
    const int lane = tid & 63;
    const int wave = tid >> 6;           // 0..7
    const int wr   = wave >> 2;          // m-half of tile (0..1)
    const int wc   = wave & 3;           // n-quarter of tile (0..3)

    // chunked-XCD mapping: XCD (id&7, dispatch round-robin) owns a 2m x 13n
    // chunk of the 8x26 tile grid (bijective: (m_t,n_t) -> xcd&3=m_t>>1,
    // loc&1=m_t&1, xcd>>2=n_t/13, loc>>1=n_t%13).
    const int id  = blockIdx.x;          // 0..207
    const int xcd = id & 7;
    const int loc = id >> 3;             // 0..25
    const int m_t = ((xcd & 3) << 1) | (loc & 1);
    const int n_t = (xcd >> 2) * 13 + (loc >> 1);
    const long tile_m = (long)m_t << 8;
    const long tile_n = (long)n_t << 8;

    // ---- staging geometry: 1 inst = 8 rows x 64 k (1 KB), linear LDS dest.
    // lane l writes LDS (row0+(l>>3), slot l&7); source k-slot pre-XORed so
    // physical slot = logical ^ (row&7).
    const int lrow = lane >> 3;                  // 0..7
    const int lcol = ((lane & 7) ^ lrow) << 3;   // fp16 elems
    const int rA1  = wave * 16 + ((wave & 4) << 4);  // rows in {0-63,128-191}
    const int rA2  = rA1 + 64;                       // rows in {64-127,192-255}
    const int rB1  = wave * 16;                      // rows 0-127
    const int rB2  = rB1 + 128;                      // rows 128-255

    const _Float16* gA = A  + (tile_m + lrow) * (long)KP + lcol;
    const _Float16* gB = Bw + lcol;

#define STAGE_A(buf, row0, k0)                                                             \
    {                                                                                      \
        __builtin_amdgcn_global_load_lds(                                                  \
            (const __attribute__((address_space(1))) void*)(gA + (long)(row0) * KP + (k0)),\
            (__attribute__((address_space(3))) void*)(&sA[buf][(row0) * 64]), 16, 0, 0);   \
        __builtin_amdgcn_global_load_lds(                                                  \
            (const __attribute__((address_space(1))) void*)(gA + (long)((row0) + 8) * KP + (k0)), \
            (__attribute__((address_space(3))) void*)(&sA[buf][((row0) + 8) * 64]), 16, 0, 0);    \
    }

// B rows >= 6432 (last n-tile only) are clamped to row 6431: finite garbage
// that feeds only the discarded output columns.
#define STAGE_B(buf, row0, k0)                                                             \
    {                                                                                      \
        long r0_ = tile_n + (row0) + lrow;     if (r0_ > 6431) r0_ = 6431;                 \
        long r1_ = r0_ + 8;                    if (r1_ > 6431) r1_ = 6431;                 \
        __builtin_amdgcn_global_load_lds(                                                  \
            (const __attribute__((address_space(1))) void*)(gB + r0_ * KP + (k0)),         \
            (__attribute__((address_space(3))) void*)(&sB[buf][(row0) * 64]), 16, 0, 0);   \
        __builtin_amdgcn_global_load_lds(                                                  \
            (const __attribute__((address_space(1))) void*)(gB + r1_ * KP + (k0)),         \
            (__attribute__((address_space(3))) void*)(&sB[buf][((row0) + 8) * 64]), 16, 0, 0);    \
    }

    // ---- fragment read offsets (swizzled slot) ----
    const int fr = lane & 15;
    const int fp = lane >> 4;                    // k-phase 0..3
    const int sw = fr & 7;                       // row&7 (frag row bases are x16)
    const int slot0 = ((fp)     ^ sw) << 3;
    const int slot1 = ((fp + 4) ^ sw) << 3;
    const int abase = (wr * 128 + fr) * 64;

    v8h af[8], bf0[2][2], bf1[2][2];
    v4f acc[8][4];
    #pragma unroll
    for (int i = 0; i < 8; ++i) {
        #pragma unroll
        for (int j = 0; j < 4; ++j) { v4f z = {0.f, 0.f, 0.f, 0.f}; acc[i][j] = z; }
    }

#define LDA(base, h) { _Pragma("unroll")                                                   \
      for (int mi = 0; mi < 4; ++mi) {                                                     \
          af[mi * 2]     = *(const v8h*)((base) + abase + (h) * 4096 + mi * 1024 + slot0); \
          af[mi * 2 + 1] = *(const v8h*)((base) + abase + (h) * 4096 + mi * 1024 + slot1); \
      } }

#define LDB(base, h, bf) { _Pragma("unroll")                                               \
      for (int ni = 0; ni < 2; ++ni) {                                                     \
          bf[ni][0] = *(const v8h*)((base) + (wc * 64 + (h) * 32 + ni * 16 + fr) * 64 + slot0); \
          bf[ni][1] = *(const v8h*)((base) + (wc * 64 + (h) * 32 + ni * 16 + fr) * 64 + slot1); \
      } }

#define MMAQ(mh, nh, bf) { _Pragma("unroll")                                               \
      for (int mi = 0; mi < 4; ++mi) { _Pragma("unroll")                                   \
          for (int ni = 0; ni < 2; ++ni) {                                                 \
              acc[(mh)*4+mi][(nh)*2+ni] = __builtin_amdgcn_mfma_f32_16x16x32_f16(          \
                  af[mi * 2],     bf[ni][0], acc[(mh)*4+mi][(nh)*2+ni], 0, 0, 0);          \
              acc[(mh)*4+mi][(nh)*2+ni] = __builtin_amdgcn_mfma_f32_16x16x32_f16(          \
                  af[mi * 2 + 1], bf[ni][1], acc[(mh)*4+mi][(nh)*2+ni], 0, 0, 0);          \
          } } }

#define ROUND(SBUF, KO, S1, S2) {                                                          \
    /* P1: read A-mh0 + B-nh0; prefetch next tile's B rows 128-255 */                      \
    LDA(sA[SBUF], 0); LDB(sB[SBUF], 0, bf0);                                               \
    if (S1) STAGE_B((SBUF) ^ 1, rB2, (KO) + 64);                                           \
    __builtin_amdgcn_s_barrier();                                                          \
    asm volatile("s_waitcnt lgkmcnt(0)" ::: "memory");                                     \
    __builtin_amdgcn_s_setprio(1);                                                         \
    MMAQ(0, 0, bf0);                                                                       \
    __builtin_amdgcn_s_setprio(0);                                                         \
    __builtin_amdgcn_s_barrier();                                                          \
    /* P2: read B-nh1; prefetch tile kt+2's A rows {0-63,128-191} */                       \
    LDB(sB[SBUF], 1, bf1);                                                                 \
    if (S2) STAGE_A(SBUF, rA1, (KO) + 128);                                                \
    __builtin_amdgcn_s_barrier();                                                          \
    asm volatile("s_waitcnt lgkmcnt(0)" ::: "memory");                                     \
    __builtin_amdgcn_s_setprio(1);                                                         \
    MMAQ(0, 1, bf1);                                                                       \
    __builtin_amdgcn_s_setprio(0);                                                         \
    __builtin_amdgcn_s_barrier();                                                          \
    /* P3: read A-mh1; prefetch tile kt+2's B rows 0-127 */                                \
    LDA(sA[SBUF], 1);                                                                      \
    if (S2) STAGE_B(SBUF, rB1, (KO) + 128);                                                \
    __builtin_amdgcn_s_barrier();                                                          \
    asm volatile("s_waitcnt lgkmcnt(0)" ::: "memory");                                     \
    __builtin_amdgcn_s_setprio(1);                                                         \
    MMAQ(1, 1, bf1);                                                                       \
    __builtin_amdgcn_s_setprio(0);                                                         \
    __builtin_amdgcn_s_barrier();                                                          \
    /* P4: prefetch tile kt+2's A rows {64-127,192-255}; counted vmcnt */                  \
    if (S2) STAGE_A(SBUF, rA2, (KO) + 128);                                                \
    __builtin_amdgcn_s_barrier();                                                          \
    __builtin_amdgcn_s_setprio(1);                                                         \
    MMAQ(1, 0, bf0);                                                                       \
    __builtin_amdgcn_s_setprio(0);                                                         \
    if (S2) { asm volatile("s_waitcnt vmcnt(6)" ::: "memory"); }                           \
    else    { asm volatile("s_waitcnt vmcnt(0)" ::: "memory"); }                           \
    __builtin_amdgcn_s_barrier(); }

    // ---- prologue: tile0 full + tile1 {A1,B1,A2} (its B2 comes at P1 of kt=0)
    STAGE_A(0, rA1, 0);  STAGE_B(0, rB1, 0);  STAGE_A(0, rA2, 0);  STAGE_B(0, rB2, 0);
    STAGE_A(1, rA1, 64); STAGE_B(1, rB1, 64); STAGE_A(1, rA2, 64);
    asm volatile("s_waitcnt vmcnt(6)" ::: "memory");   // tile0's 8 landed
    __builtin_amdgcn_s_barrier();

    for (int kt = 0; kt < 100; kt += 2) {
        ROUND(0, kt * 64,       1, 1);
        ROUND(1, kt * 64 + 64,  1, 1);
    }
    ROUND(0, 6400, 1, 0);   // kt=100: stage B(101) rows128-255 only; drain all
    ROUND(1, 6464, 0, 0);   // kt=101: compute only

    // ---- epilogue: C/D layout col=lane&15, row=(lane>>4)*4+reg (m89-verified)
    #pragma unroll
    for (int j = 0; j < 4; ++j) {
        const long col = tile_n + (wc << 6) + (j << 4) + fr;
        if (col < KP) {
            const bool val = col < GN;
            const float bv = val ? bias[col] : 0.f;
            #pragma unroll
            for (int i = 0; i < 8; ++i) {
                const long row = tile_m + wr * 128 + (i << 4) + (fp << 2);
                #pragma unroll
                for (int r = 0; r < 4; ++r) {
                    float v = acc[i][j][r] + bv;
                    v = v > 0.f ? v : 0.f;
                    // pad cols [6432,6528) get 0 (K-pad of next GEMM's A)
                    C[(row + r) * (long)KP + col] = val ? (_Float16)v : (_Float16)0.f;
                }
            }
        }
    }

#undef STAGE_A
#undef STAGE_B
#undef LDA
#undef LDB
#undef MMAQ
#undef ROUND
}

// ---------------------------------------------------------------------------
// Final projection: out[b,o] = sum_k F[b,k]*wo[o,k] + bo[o].
// ---------------------------------------------------------------------------
__global__ __launch_bounds__(256) void final_out(
    const _Float16* __restrict__ F, const float* __restrict__ wo,
    const float* __restrict__ bo, float* __restrict__ out)
{
    __shared__ float red[4][8];
    const long b   = blockIdx.x;
    const int tid  = threadIdx.x;
    const int lane = tid & 63;
    const int wave = tid >> 6;
    float acc[5] = {0.f, 0.f, 0.f, 0.f, 0.f};
    const _Float16* f = F + b * KP;

    const int c1 = (wave + 1) * 402;
    for (int c = wave * 402 + lane; c < c1; c += 64) {
        const int k = c << 2;
        v4h f4 = *(const v4h*)(f + k);
        const float f0 = (float)f4[0], f1 = (float)f4[1];
        const float f2 = (float)f4[2], f3 = (float)f4[3];
        #pragma unroll
        for (int o = 0; o < 5; ++o) {
            const float4 w4 = *(const float4*)(wo + o * GK + k);
            acc[o] += f0 * w4.x + f1 * w4.y + f2 * w4.z + f3 * w4.w;
        }
    }
    #pragma unroll
    for (int o = 0; o < 5; ++o) {
        #pragma unroll
        for (int off = 32; off > 0; off >>= 1) acc[o] += __shfl_down(acc[o], off, 64);
    }
    if (lane == 0) {
        #pragma unroll
        for (int o = 0; o < 5; ++o) red[wave][o] = acc[o];
    }
    __syncthreads();
    if (tid < 5)
        out[b * 5 + tid] = red[0][tid] + red[1][tid] + red[2][tid] + red[3][tid] + bo[tid];
}

// ---------------------------------------------------------------------------
extern "C" void kernel_launch(void* const* d_in, const int* in_sizes, int n_in,
                              void* d_out, int out_size, void* d_ws, size_t ws_size,
                              hipStream_t stream)
{
    const float* x  = (const float*)d_in[0];
    const float* w1 = (const float*)d_in[1];
    const float* b1 = (const float*)d_in[2];
    const float* w2 = (const float*)d_in[3];
    const float* b2 = (const float*)d_in[4];
    const float* wl = (const float*)d_in[5];
    const float* bl = (const float*)d_in[6];
    const float* wo = (const float*)d_in[7];
    const float* bo = (const float*)d_in[8];
    float* out = (float*)d_out;

    char* ws = (char*)d_ws;
    _Float16* Wh = (_Float16*)ws;                                   // 6432*6528*2 = 83,976,192 B
    _Float16* F0 = (_Float16*)(ws + 83976192);                      // 2048*6528*2 = 26,738,688 B
    _Float16* F1 = (_Float16*)(ws + 83976192 + 26738688);

    convert_w<<<dim3(7, GN), 256, 0, stream>>>(wl, Wh);
    conv_feat<<<GM, 256, 0, stream>>>(x, w1, b1, w2, b2, F0);
    gemm8<<<208, 512, 0, stream>>>(F0, Wh, bl, F1);
    gemm8<<<208, 512, 0, stream>>>(F1, Wh, bl, F0);
    gemm8<<<208, 512, 0, stream>>>(F0, Wh, bl, F1);
    gemm8<<<208, 512, 0, stream>>>(F1, Wh, bl, F0);
    final_out<<<GM, 256, 0, stream>>>(F0, wo, bo, out);
}